// Round 4
// baseline (106.771 us; speedup 1.0000x reference)
//
#include <hip/hip_runtime.h>
#include <hip/hip_bf16.h>

#define N_ROWS 2048
#define D_IN   256
#define D_OUT  64
#define JSLAB  8
#define NBLK   512
#define ALPHA  0.2f
#define LN_EPS 1e-5f

typedef __attribute__((ext_vector_type(4))) float f32x4;
typedef __attribute__((ext_vector_type(8))) short s16x8;

static __device__ __forceinline__ unsigned short f2bf(float x) {
    unsigned u = __float_as_uint(x);
    unsigned r = (u + 0x7FFFu + ((u >> 16) & 1u)) >> 16;   // RTN-even
    return (unsigned short)r;
}
static __device__ __forceinline__ float bf2f(unsigned short u) {
    return __uint_as_float(((unsigned)u) << 16);
}

// ---------------------------------------------------------------------------
// Fused GAT head, single kernel + software grid barrier.
// 512 blocks x 256 threads. LDS 33.8KB, VGPR<=256 -> >=2 blocks/CU resident
// (512 total) guaranteed; spin barrier cannot deadlock.
// Phase 1: block computes 4 h-rows (LN, s, H^T bf16 hi/lo).
// Barrier:  monotone arrival counter (memset to 0 per launch by host node).
// Phase 2: block runs 2 slab-tasks of stripe (bid>>2): 16x256 W tile -> MFMA.
// Finish:  4th block to complete a stripe combines partials, ELU, store.
// ---------------------------------------------------------------------------
__global__ __launch_bounds__(256, 2) void fused_gat(
    const float* __restrict__ F, const int* __restrict__ adj,
    const float* __restrict__ phiW, const float* __restrict__ phiB,
    const float* __restrict__ lnG, const float* __restrict__ lnB,
    const float* __restrict__ muW, const float* __restrict__ muB,
    int* __restrict__ bar,                    // [0]=global cnt, [1+stripe]=stripe cnt
    float* __restrict__ s_buf, float* __restrict__ l_p,
    float* __restrict__ numP, unsigned short* __restrict__ HhiT,
    unsigned short* __restrict__ HloT, float* __restrict__ out)
{
    __shared__ union {
        struct {
            f32x4 phiS[64 * 32];                 // 32 KB (one k-half, swizzled)
            unsigned short Thi[64][4];
            unsigned short Tlo[64][4];
        } p1;
        struct {
            unsigned short Wt[4][16][72];
            f32x4 cN[4][4][64];
            f32x4 cL[4][64];
        } p2;
    } sm;
    __shared__ int finisher;

    const int tid  = threadIdx.x;
    const int w    = tid >> 6;
    const int lane = tid & 63;
    const int bid  = blockIdx.x;

    // ================= Phase 1: h, LN, s, H^T (4 rows/block) ===============
    {
        const int r = bid * 4 + w;                 // one row per wave
        const f32x4* phiW4 = (const f32x4*)phiW;   // [64][64] f32x4
        const f32x4* F4    = (const f32x4*)F;      // [2048][64] f32x4

        float acc0 = 0.f, acc1 = 0.f;
        for (int half = 0; half < 2; ++half) {
            __syncthreads();
            #pragma unroll
            for (int t = 0; t < 8; ++t) {
                int idx = tid + t * 256;
                int d = idx >> 5, g = idx & 31;
                sm.p1.phiS[(d << 5) | (g ^ (d & 7))] = phiW4[d * 64 + half * 32 + g];
            }
            __syncthreads();
            #pragma unroll
            for (int g = 0; g < 32; ++g) {
                f32x4 p = sm.p1.phiS[(lane << 5) | (g ^ (lane & 7))];
                f32x4 f = F4[r * 64 + half * 32 + g];
                float d0 = p.x * f.x + p.y * f.y + p.z * f.z + p.w * f.w;
                if (g & 1) acc1 += d0; else acc0 += d0;
            }
        }

        const float pb = phiB[lane], gg = lnG[lane], bb = lnB[lane], mw = muW[lane];
        float h = acc0 + acc1 + pb;
        float m = h;
        #pragma unroll
        for (int off = 32; off >= 1; off >>= 1) m += __shfl_xor(m, off);
        m *= (1.f / 64.f);
        float c = h - m;
        float v = c * c;
        #pragma unroll
        for (int off = 32; off >= 1; off >>= 1) v += __shfl_xor(v, off);
        v *= (1.f / 64.f);
        float hn = c * rsqrtf(v + LN_EPS) * gg + bb;
        float sp = hn * mw;
        #pragma unroll
        for (int off = 32; off >= 1; off >>= 1) sp += __shfl_xor(sp, off);
        if (lane == 0) s_buf[r] = sp;
        unsigned short hi = f2bf(hn);
        unsigned short lo = f2bf(hn - bf2f(hi));
        sm.p1.Thi[lane][w] = hi;
        sm.p1.Tlo[lane][w] = lo;
        __syncthreads();
        if (tid < 64) {
            *(ushort4*)&HhiT[tid * N_ROWS + bid * 4] = *(const ushort4*)&sm.p1.Thi[tid][0];
        } else if (tid < 128) {
            int d = tid - 64;
            *(ushort4*)&HloT[d * N_ROWS + bid * 4] = *(const ushort4*)&sm.p1.Tlo[d][0];
        }
    }

    // ================= Global barrier (arrival counting) ===================
    __syncthreads();                       // drains vmem (compiler waitcnt)
    if (tid == 0) {
        __threadfence();                   // release: L2 writeback
        atomicAdd(&bar[0], 1);
        while (atomicAdd(&bar[0], 0) < NBLK) __builtin_amdgcn_s_sleep(1);
        __threadfence();                   // acquire: invalidate stale L2
    }
    __syncthreads();

    // ================= Phase 2: two slab-tasks of stripe bid>>2 ============
    const int stripe = bid >> 2;
    const int i0 = stripe * 16;
    const float mub = muB[0];
    const int rsel = lane & 15;
    const int rsub = lane >> 4;

    s16x8 ones;
    #pragma unroll
    for (int e = 0; e < 8; ++e) ones[e] = (short)0x3F80;  // bf16 1.0

    #pragma unroll
    for (int t = 0; t < 2; ++t) {
        const int slab = (bid * 2 + t) & 7;
        const int jb = slab * 256 + w * 64;

        f32x4 accN[4];
        f32x4 accL;
        #pragma unroll
        for (int nb = 0; nb < 4; ++nb) { accN[nb][0]=0.f; accN[nb][1]=0.f; accN[nb][2]=0.f; accN[nb][3]=0.f; }
        accL[0]=0.f; accL[1]=0.f; accL[2]=0.f; accL[3]=0.f;

        __syncthreads();   // protect cN/cL from previous iteration's readers

        // ---- build 16x64 W tile: int4 adj loads, 4 rows/iteration
        const float4 sj4 = ((const float4*)s_buf)[(jb >> 2) + rsel];
        const int4* adj4 = (const int4*)adj;
        #pragma unroll
        for (int r4 = 0; r4 < 4; ++r4) {
            const int row = r4 * 4 + rsub;
            const int i = i0 + row;
            const float si = s_buf[i];
            int4 a = adj4[(size_t)i * (N_ROWS / 4) + (jb >> 2) + rsel];
            ushort4 pk;
            { float z = si + sj4.x + mub; float e = z > 0.f ? z : ALPHA * z; pk.x = a.x ? f2bf(__expf(e)) : 0; }
            { float z = si + sj4.y + mub; float e = z > 0.f ? z : ALPHA * z; pk.y = a.y ? f2bf(__expf(e)) : 0; }
            { float z = si + sj4.z + mub; float e = z > 0.f ? z : ALPHA * z; pk.z = a.z ? f2bf(__expf(e)) : 0; }
            { float z = si + sj4.w + mub; float e = z > 0.f ? z : ALPHA * z; pk.w = a.w ? f2bf(__expf(e)) : 0; }
            *(ushort4*)&sm.p2.Wt[w][row][rsel * 4] = pk;
        }

        // ---- A fragments (same-wave LDS dependency)
        s16x8 a0 = *(const s16x8*)&sm.p2.Wt[w][rsel][rsub * 8];
        s16x8 a1 = *(const s16x8*)&sm.p2.Wt[w][rsel][32 + rsub * 8];

        accL = __builtin_amdgcn_mfma_f32_16x16x32_bf16(a0, ones, accL, 0, 0, 0);
        accL = __builtin_amdgcn_mfma_f32_16x16x32_bf16(a1, ones, accL, 0, 0, 0);
        #pragma unroll
        for (int nb = 0; nb < 4; ++nb) {
            const unsigned short* hr = HhiT + (size_t)(nb * 16 + rsel) * N_ROWS + jb + rsub * 8;
            s16x8 b0 = *(const s16x8*)hr;
            s16x8 b1 = *(const s16x8*)(hr + 32);
            accN[nb] = __builtin_amdgcn_mfma_f32_16x16x32_bf16(a0, b0, accN[nb], 0, 0, 0);
            accN[nb] = __builtin_amdgcn_mfma_f32_16x16x32_bf16(a1, b1, accN[nb], 0, 0, 0);
            const unsigned short* lr = HloT + (size_t)(nb * 16 + rsel) * N_ROWS + jb + rsub * 8;
            s16x8 c0 = *(const s16x8*)lr;
            s16x8 c1 = *(const s16x8*)(lr + 32);
            accN[nb] = __builtin_amdgcn_mfma_f32_16x16x32_bf16(a0, c0, accN[nb], 0, 0, 0);
            accN[nb] = __builtin_amdgcn_mfma_f32_16x16x32_bf16(a1, c1, accN[nb], 0, 0, 0);
        }

        // ---- cross-wave combine
        #pragma unroll
        for (int nb = 0; nb < 4; ++nb) sm.p2.cN[w][nb][lane] = accN[nb];
        sm.p2.cL[w][lane] = accL;
        __syncthreads();

        {   // wave w handles column-block nb = w
            f32x4 n = sm.p2.cN[0][w][lane] + sm.p2.cN[1][w][lane]
                    + sm.p2.cN[2][w][lane] + sm.p2.cN[3][w][lane];
            float* np = numP + (size_t)slab * (N_ROWS * D_OUT);
            #pragma unroll
            for (int r = 0; r < 4; ++r)
                np[(i0 + rsub * 4 + r) * D_OUT + w * 16 + rsel] = n[r];
        }
        if (w == 0) {
            f32x4 l = sm.p2.cL[0][lane] + sm.p2.cL[1][lane]
                    + sm.p2.cL[2][lane] + sm.p2.cL[3][lane];
            if (rsel == 0) {
                #pragma unroll
                for (int r = 0; r < 4; ++r)
                    l_p[slab * N_ROWS + i0 + rsub * 4 + r] = l[r];
            }
        }
    }

    // ================= Stripe completion: last of 4 blocks finishes ========
    __syncthreads();                       // drain this block's numP stores
    if (tid == 0) {
        __threadfence();                   // release partials
        int old = atomicAdd(&bar[1 + stripe], 1);
        finisher = (old == 3);
        if (old == 3) __threadfence();     // acquire others' partials
    }
    __syncthreads();

    if (finisher) {
        // 1024 outputs (16 rows x 64 d), 256 threads -> f32x4 per thread
        const int idx = tid * 4;
        const int r = idx >> 6;
        const int c = idx & 63;
        const int row = i0 + r;
        f32x4 n = {0.f, 0.f, 0.f, 0.f};
        float l = 0.f;
        #pragma unroll
        for (int sl = 0; sl < JSLAB; ++sl) {
            const f32x4* np = (const f32x4*)(numP + (size_t)sl * (N_ROWS * D_OUT)
                                             + row * D_OUT + c);
            n += *np;
            l += l_p[sl * N_ROWS + row];
        }
        const float inv = 1.f / l;
        f32x4 o;
        #pragma unroll
        for (int e = 0; e < 4; ++e) {
            float v = n[e] * inv;
            o[e] = v > 0.f ? v : expm1f(v);
        }
        *(f32x4*)&out[row * D_OUT + c] = o;
    }
}

// ---------------------------------------------------------------------------
extern "C" void kernel_launch(void* const* d_in, const int* in_sizes, int n_in,
                              void* d_out, int out_size, void* d_ws, size_t ws_size,
                              hipStream_t stream)
{
    const float* F    = (const float*)d_in[0];
    const int*   adj  = (const int*)d_in[1];
    const float* phiW = (const float*)d_in[2];
    const float* phiB = (const float*)d_in[3];
    const float* lnG  = (const float*)d_in[4];
    const float* lnB  = (const float*)d_in[5];
    const float* muW  = (const float*)d_in[6];
    const float* muB  = (const float*)d_in[7];
    float* out = (float*)d_out;

    int*   bar  = (int*)d_ws;                           // [0] + [128] counters
    float* ws   = (float*)d_ws + 256;
    float* s    = ws;                                   // 2048 f32
    float* l_p  = ws + N_ROWS;                          // JSLAB*2048 f32
    float* numP = l_p + (size_t)JSLAB * N_ROWS;         // JSLAB*2048*64 f32
    unsigned short* HhiT = (unsigned short*)(numP + (size_t)JSLAB * N_ROWS * D_OUT);
    unsigned short* HloT = HhiT + (size_t)D_OUT * N_ROWS;

    hipMemsetAsync(bar, 0, 256 * sizeof(int), stream);  // reset barrier state

    fused_gat<<<dim3(NBLK), dim3(256), 0, stream>>>(
        F, adj, phiW, phiB, lnG, lnB, muW, muB,
        bar, s, l_p, numP, HhiT, HloT, out);
}

// Round 5
// 39.896 us; speedup vs baseline: 2.6763x; 2.6763x over previous
//
#include <hip/hip_runtime.h>
#include <hip/hip_bf16.h>

#define N_ROWS 2048
#define D_IN   256
#define D_OUT  64
#define JSLAB  8
#define NBLK   512
#define NLEAF  64        // barrier arrival tree leaves (8 blocks each)
#define ALPHA  0.2f
#define LN_EPS 1e-5f

typedef __attribute__((ext_vector_type(4))) float f32x4;
typedef __attribute__((ext_vector_type(8))) short s16x8;

static __device__ __forceinline__ unsigned short f2bf(float x) {
    unsigned u = __float_as_uint(x);
    unsigned r = (u + 0x7FFFu + ((u >> 16) & 1u)) >> 16;   // RTN-even
    return (unsigned short)r;
}
static __device__ __forceinline__ float bf2f(unsigned short u) {
    return __uint_as_float(((unsigned)u) << 16);
}
static __device__ __forceinline__ void st_agent_f32(float* p, float v) {
    __hip_atomic_store(p, v, __ATOMIC_RELAXED, __HIP_MEMORY_SCOPE_AGENT);
}
static __device__ __forceinline__ void st_agent_u64(void* p, unsigned long long v) {
    __hip_atomic_store((unsigned long long*)p, v, __ATOMIC_RELAXED, __HIP_MEMORY_SCOPE_AGENT);
}

// ---------------------------------------------------------------------------
// Fused GAT head, single kernel + software grid barrier (load-polled).
// 512 blocks x 256 threads; LDS union ~65KB -> 2 blocks/CU, residency
// guaranteed (512 total), spin cannot deadlock.
// All cross-block stores are agent-scope (sc1, write-through): no wbl2 fences.
// Phase 1: block computes 4 h-rows (LN, s, H^T bf16 hi/lo), sc1 stores.
// Barrier: 64 leaf counters -> root; poll root with relaxed agent LOADS.
// Phase 2: 2 slab-tasks of stripe bid>>2: 16x256 W tile -> MFMA partials.
// Finish:  4th block of a stripe combines partials, ELU, plain store to out.
// ---------------------------------------------------------------------------
__global__ __launch_bounds__(256, 2) void fused_gat(
    const float* __restrict__ F, const int* __restrict__ adj,
    const float* __restrict__ phiW, const float* __restrict__ phiB,
    const float* __restrict__ lnG, const float* __restrict__ lnB,
    const float* __restrict__ muW, const float* __restrict__ muB,
    int* __restrict__ bar,      // [0]=root, [16+leaf*16]=leaves, [1040+stripe]
    float* __restrict__ s_buf, float* __restrict__ l_p,
    float* __restrict__ numP, unsigned short* __restrict__ HhiT,
    unsigned short* __restrict__ HloT, float* __restrict__ out)
{
    __shared__ union {
        struct {
            f32x4 phiS[64 * 64];                 // 64 KB, column-rotated
            unsigned short Thi[64][4];
            unsigned short Tlo[64][4];
        } p1;
        struct {
            unsigned short Wt[4][16][72];
            f32x4 cN[4][4][64];
            f32x4 cL[4][64];
        } p2;
    } sm;
    __shared__ int finisher;

    const int tid  = threadIdx.x;
    const int w    = tid >> 6;
    const int lane = tid & 63;
    const int bid  = blockIdx.x;

    // ================= Phase 1: h, LN, s, H^T (4 rows/block) ===============
    {
        const int r = bid * 4 + w;                 // one row per wave
        const f32x4* phiW4 = (const f32x4*)phiW;   // [64][64] f32x4
        const f32x4* F4    = (const f32x4*)F;      // [2048][64] f32x4

        #pragma unroll
        for (int t = 0; t < 16; ++t) {             // stage 64KB, rotated cols
            int idx = tid + t * 256;
            int d = idx >> 6, g = idx & 63;
            sm.p1.phiS[(d << 6) | ((g + d) & 63)] = phiW4[idx];
        }
        __syncthreads();

        float acc0 = 0.f, acc1 = 0.f;
        #pragma unroll 8
        for (int g = 0; g < 64; ++g) {
            f32x4 p = sm.p1.phiS[(lane << 6) | ((g + lane) & 63)];
            f32x4 f = F4[r * 64 + g];
            float d0 = p.x * f.x + p.y * f.y + p.z * f.z + p.w * f.w;
            if (g & 1) acc1 += d0; else acc0 += d0;
        }

        const float pb = phiB[lane], gg = lnG[lane], bb = lnB[lane], mw = muW[lane];
        float h = acc0 + acc1 + pb;
        float m = h;
        #pragma unroll
        for (int off = 32; off >= 1; off >>= 1) m += __shfl_xor(m, off);
        m *= (1.f / 64.f);
        float c = h - m;
        float v = c * c;
        #pragma unroll
        for (int off = 32; off >= 1; off >>= 1) v += __shfl_xor(v, off);
        v *= (1.f / 64.f);
        float hn = c * rsqrtf(v + LN_EPS) * gg + bb;
        float sp = hn * mw;
        #pragma unroll
        for (int off = 32; off >= 1; off >>= 1) sp += __shfl_xor(sp, off);
        if (lane == 0) st_agent_f32(&s_buf[r], sp);
        unsigned short hi = f2bf(hn);
        unsigned short lo = f2bf(hn - bf2f(hi));
        sm.p1.Thi[lane][w] = hi;
        sm.p1.Tlo[lane][w] = lo;
        __syncthreads();
        if (tid < 64) {          // H^T[d][bid*4 .. +3], 8B agent stores
            st_agent_u64(&HhiT[tid * N_ROWS + bid * 4],
                         *(const unsigned long long*)&sm.p1.Thi[tid][0]);
        } else if (tid < 128) {
            int d = tid - 64;
            st_agent_u64(&HloT[d * N_ROWS + bid * 4],
                         *(const unsigned long long*)&sm.p1.Tlo[d][0]);
        }
    }

    // ================= Global barrier: tree arrival, load-polling ==========
    __syncthreads();     // each wave drains vmcnt before s_barrier (compiler)
    if (tid == 0) {
        const int leaf = bid >> 3;                 // 8 blocks per leaf
        if (atomicAdd(&bar[16 + leaf * 16], 1) == 7)
            atomicAdd(&bar[0], 1);
        while (__hip_atomic_load(&bar[0], __ATOMIC_RELAXED,
                                 __HIP_MEMORY_SCOPE_AGENT) < NLEAF)
            __builtin_amdgcn_s_sleep(32);
    }
    __syncthreads();

    // ================= Phase 2: two slab-tasks of stripe bid>>2 ============
    const int stripe = bid >> 2;
    const int i0 = stripe * 16;
    const float mub = muB[0];
    const int rsel = lane & 15;
    const int rsub = lane >> 4;

    s16x8 ones;
    #pragma unroll
    for (int e = 0; e < 8; ++e) ones[e] = (short)0x3F80;  // bf16 1.0

    #pragma unroll
    for (int t = 0; t < 2; ++t) {
        const int slab = (bid * 2 + t) & 7;
        const int jb = slab * 256 + w * 64;

        f32x4 accN[4];
        f32x4 accL;
        #pragma unroll
        for (int nb = 0; nb < 4; ++nb) { accN[nb][0]=0.f; accN[nb][1]=0.f; accN[nb][2]=0.f; accN[nb][3]=0.f; }
        accL[0]=0.f; accL[1]=0.f; accL[2]=0.f; accL[3]=0.f;

        __syncthreads();   // protect cN/cL (and p1->p2 union transition)

        // ---- build 16x64 W tile: int4 adj loads, 4 rows/iteration
        const float4 sj4 = ((const float4*)s_buf)[(jb >> 2) + rsel];
        const int4* adj4 = (const int4*)adj;
        #pragma unroll
        for (int r4 = 0; r4 < 4; ++r4) {
            const int row = r4 * 4 + rsub;
            const int i = i0 + row;
            const float si = s_buf[i];
            int4 a = adj4[(size_t)i * (N_ROWS / 4) + (jb >> 2) + rsel];
            ushort4 pk;
            { float z = si + sj4.x + mub; float e = z > 0.f ? z : ALPHA * z; pk.x = a.x ? f2bf(__expf(e)) : 0; }
            { float z = si + sj4.y + mub; float e = z > 0.f ? z : ALPHA * z; pk.y = a.y ? f2bf(__expf(e)) : 0; }
            { float z = si + sj4.z + mub; float e = z > 0.f ? z : ALPHA * z; pk.z = a.z ? f2bf(__expf(e)) : 0; }
            { float z = si + sj4.w + mub; float e = z > 0.f ? z : ALPHA * z; pk.w = a.w ? f2bf(__expf(e)) : 0; }
            *(ushort4*)&sm.p2.Wt[w][row][rsel * 4] = pk;
        }

        // ---- A fragments (same-wave LDS dependency)
        s16x8 a0 = *(const s16x8*)&sm.p2.Wt[w][rsel][rsub * 8];
        s16x8 a1 = *(const s16x8*)&sm.p2.Wt[w][rsel][32 + rsub * 8];

        accL = __builtin_amdgcn_mfma_f32_16x16x32_bf16(a0, ones, accL, 0, 0, 0);
        accL = __builtin_amdgcn_mfma_f32_16x16x32_bf16(a1, ones, accL, 0, 0, 0);
        #pragma unroll
        for (int nb = 0; nb < 4; ++nb) {
            const unsigned short* hr = HhiT + (size_t)(nb * 16 + rsel) * N_ROWS + jb + rsub * 8;
            s16x8 b0 = *(const s16x8*)hr;
            s16x8 b1 = *(const s16x8*)(hr + 32);
            accN[nb] = __builtin_amdgcn_mfma_f32_16x16x32_bf16(a0, b0, accN[nb], 0, 0, 0);
            accN[nb] = __builtin_amdgcn_mfma_f32_16x16x32_bf16(a1, b1, accN[nb], 0, 0, 0);
            const unsigned short* lr = HloT + (size_t)(nb * 16 + rsel) * N_ROWS + jb + rsub * 8;
            s16x8 c0 = *(const s16x8*)lr;
            s16x8 c1 = *(const s16x8*)(lr + 32);
            accN[nb] = __builtin_amdgcn_mfma_f32_16x16x32_bf16(a0, c0, accN[nb], 0, 0, 0);
            accN[nb] = __builtin_amdgcn_mfma_f32_16x16x32_bf16(a1, c1, accN[nb], 0, 0, 0);
        }

        // ---- cross-wave combine
        #pragma unroll
        for (int nb = 0; nb < 4; ++nb) sm.p2.cN[w][nb][lane] = accN[nb];
        sm.p2.cL[w][lane] = accL;
        __syncthreads();

        {   // wave w handles column-block nb = w; agent stores (sc1)
            f32x4 n = sm.p2.cN[0][w][lane] + sm.p2.cN[1][w][lane]
                    + sm.p2.cN[2][w][lane] + sm.p2.cN[3][w][lane];
            float* np = numP + (size_t)slab * (N_ROWS * D_OUT);
            #pragma unroll
            for (int r = 0; r < 4; ++r)
                st_agent_f32(&np[(i0 + rsub * 4 + r) * D_OUT + w * 16 + rsel], n[r]);
        }
        if (w == 0) {
            f32x4 l = sm.p2.cL[0][lane] + sm.p2.cL[1][lane]
                    + sm.p2.cL[2][lane] + sm.p2.cL[3][lane];
            if (rsel == 0) {
                // l_p layout: [stripe][slab][16] -> stripe-exclusive 512B
                #pragma unroll
                for (int r = 0; r < 4; ++r)
                    st_agent_f32(&l_p[stripe * 128 + slab * 16 + rsub * 4 + r], l[r]);
            }
        }
    }

    // ================= Stripe completion: last of 4 blocks finishes ========
    __syncthreads();                       // drain this block's sc1 stores
    if (tid == 0) {
        int old = atomicAdd(&bar[1040 + stripe], 1);
        finisher = (old == 3);
    }
    __syncthreads();

    if (finisher) {
        // 1024 outputs (16 rows x 64 d), 256 threads -> f32x4 per thread
        const int idx = tid * 4;
        const int r = idx >> 6;
        const int c = idx & 63;
        const int row = i0 + r;
        f32x4 n = {0.f, 0.f, 0.f, 0.f};
        float l = 0.f;
        #pragma unroll
        for (int sl = 0; sl < JSLAB; ++sl) {
            const f32x4* np = (const f32x4*)(numP + (size_t)sl * (N_ROWS * D_OUT)
                                             + row * D_OUT + c);
            n += *np;
            l += l_p[stripe * 128 + sl * 16 + r];
        }
        const float inv = 1.f / l;
        f32x4 o;
        #pragma unroll
        for (int e = 0; e < 4; ++e) {
            float v = n[e] * inv;
            o[e] = v > 0.f ? v : expm1f(v);
        }
        *(f32x4*)&out[row * D_OUT + c] = o;
    }
}

// ---------------------------------------------------------------------------
extern "C" void kernel_launch(void* const* d_in, const int* in_sizes, int n_in,
                              void* d_out, int out_size, void* d_ws, size_t ws_size,
                              hipStream_t stream)
{
    const float* F    = (const float*)d_in[0];
    const int*   adj  = (const int*)d_in[1];
    const float* phiW = (const float*)d_in[2];
    const float* phiB = (const float*)d_in[3];
    const float* lnG  = (const float*)d_in[4];
    const float* lnB  = (const float*)d_in[5];
    const float* muW  = (const float*)d_in[6];
    const float* muB  = (const float*)d_in[7];
    float* out = (float*)d_out;

    int*   bar  = (int*)d_ws;                           // 2048 ints reserved
    float* ws   = (float*)d_ws + 2048;
    float* s    = ws;                                   // 2048 f32
    float* l_p  = ws + N_ROWS;                          // 128*128 f32 (padded)
    float* numP = l_p + 128 * 128;                      // JSLAB*2048*64 f32
    unsigned short* HhiT = (unsigned short*)(numP + (size_t)JSLAB * N_ROWS * D_OUT);
    unsigned short* HloT = HhiT + (size_t)D_OUT * N_ROWS;

    hipMemsetAsync(bar, 0, 2048 * sizeof(int), stream); // reset barrier state

    fused_gat<<<dim3(NBLK), dim3(256), 0, stream>>>(
        F, adj, phiW, phiB, lnG, lnB, muW, muB,
        bar, s, l_p, numP, HhiT, HloT, out);
}

// Round 6
// 32.393 us; speedup vs baseline: 3.2961x; 1.2316x over previous
//
#include <hip/hip_runtime.h>
#include <hip/hip_bf16.h>

#define N_ROWS 2048
#define D_IN   256
#define D_OUT  64
#define JSLAB  8
#define ALPHA  0.2f
#define LN_EPS 1e-5f

typedef __attribute__((ext_vector_type(4))) float f32x4;
typedef __attribute__((ext_vector_type(8))) short s16x8;

static __device__ __forceinline__ unsigned short f2bf(float x) {
    unsigned u = __float_as_uint(x);
    unsigned r = (u + 0x7FFFu + ((u >> 16) & 1u)) >> 16;   // RTN-even
    return (unsigned short)r;
}
static __device__ __forceinline__ float bf2f(unsigned short u) {
    return __uint_as_float(((unsigned)u) << 16);
}
static __device__ __forceinline__ void st_agent_f32(float* p, float v) {
    __hip_atomic_store(p, v, __ATOMIC_RELAXED, __HIP_MEMORY_SCOPE_AGENT);
}

// ---------------------------------------------------------------------------
// K1: h = LN(F@phiW^T + b); s = h.muW; H^T bf16 hi/lo planes.
// 512 blocks x 256 threads, 4 rows/block (1 row/wave). Plain stores; K1->K2
// visibility via dispatch-boundary release (same mechanism as the passing
// 3-kernel version). LDS ~65KB -> 2 blocks/CU, no residency requirement.
// ---------------------------------------------------------------------------
__global__ __launch_bounds__(256) void k1_h_s(
    const float* __restrict__ F, const float* __restrict__ phiW,
    const float* __restrict__ phiB, const float* __restrict__ lnG,
    const float* __restrict__ lnB, const float* __restrict__ muW,
    float* __restrict__ s_buf, unsigned short* __restrict__ HhiT,
    unsigned short* __restrict__ HloT)
{
    __shared__ f32x4 phiS[64 * 64];          // 64 KB, column-rotated
    __shared__ unsigned short Thi[64][4];
    __shared__ unsigned short Tlo[64][4];

    const int tid  = threadIdx.x;
    const int w    = tid >> 6;
    const int lane = tid & 63;
    const int bid  = blockIdx.x;
    const int r    = bid * 4 + w;              // one row per wave

    const f32x4* phiW4 = (const f32x4*)phiW;   // [64][64] f32x4
    const f32x4* F4    = (const f32x4*)F;      // [2048][64] f32x4

    #pragma unroll
    for (int t = 0; t < 16; ++t) {             // stage 64KB, rotated cols
        int idx = tid + t * 256;
        int d = idx >> 6, g = idx & 63;
        phiS[(d << 6) | ((g + d) & 63)] = phiW4[idx];
    }
    __syncthreads();

    float acc0 = 0.f, acc1 = 0.f;
    #pragma unroll 8
    for (int g = 0; g < 64; ++g) {
        f32x4 p = phiS[(lane << 6) | ((g + lane) & 63)];
        f32x4 f = F4[r * 64 + g];              // wave-uniform address
        float d0 = p.x * f.x + p.y * f.y + p.z * f.z + p.w * f.w;
        if (g & 1) acc1 += d0; else acc0 += d0;
    }

    const float pb = phiB[lane], gg = lnG[lane], bb = lnB[lane], mw = muW[lane];
    float h = acc0 + acc1 + pb;
    float m = h;
    #pragma unroll
    for (int off = 32; off >= 1; off >>= 1) m += __shfl_xor(m, off);
    m *= (1.f / 64.f);
    float c = h - m;
    float v = c * c;
    #pragma unroll
    for (int off = 32; off >= 1; off >>= 1) v += __shfl_xor(v, off);
    v *= (1.f / 64.f);
    float hn = c * rsqrtf(v + LN_EPS) * gg + bb;
    float sp = hn * mw;
    #pragma unroll
    for (int off = 32; off >= 1; off >>= 1) sp += __shfl_xor(sp, off);
    if (lane == 0) s_buf[r] = sp;
    unsigned short hi = f2bf(hn);
    unsigned short lo = f2bf(hn - bf2f(hi));
    Thi[lane][w] = hi;
    Tlo[lane][w] = lo;
    __syncthreads();
    if (tid < 64) {          // H^T[d][bid*4 .. +3], 8B stores
        *(ushort4*)&HhiT[tid * N_ROWS + bid * 4] = *(const ushort4*)&Thi[tid][0];
    } else if (tid < 128) {
        int d = tid - 64;
        *(ushort4*)&HloT[d * N_ROWS + bid * 4] = *(const ushort4*)&Tlo[d][0];
    }
}

// ---------------------------------------------------------------------------
// K2: 1024 blocks x 256 threads; block = one (stripe, slab) task:
// 16 rows x 256 j. Wave w owns 16x64 W tile -> MFMA numerator/denominator,
// cross-wave LDS combine, sc1 partial stores. Last of a stripe's 8 blocks
// (per-stripe counter) combines 8 slab partials, normalizes, ELU, stores out.
// LDS ~30KB -> 4 blocks/CU resident (16 waves/CU).
// ---------------------------------------------------------------------------
__global__ __launch_bounds__(256) void k2_attn(
    const int* __restrict__ adj, const float* __restrict__ s_buf,
    const unsigned short* __restrict__ HhiT, const unsigned short* __restrict__ HloT,
    const float* __restrict__ muB, int* __restrict__ bar,
    float* __restrict__ numP, float* __restrict__ l_p,
    float* __restrict__ out)
{
    __shared__ __align__(16) unsigned short Wt[4][16][72];
    __shared__ f32x4 cN[4][4][64];
    __shared__ f32x4 cL[4][64];
    __shared__ int finisher;

    const int tid  = threadIdx.x;
    const int w    = tid >> 6;
    const int lane = tid & 63;
    const int stripe = blockIdx.x >> 3;        // 0..127
    const int slab   = blockIdx.x & 7;         // 0..7
    const int i0 = stripe * 16;
    const int jb = slab * 256 + w * 64;
    const float mub = muB[0];

    const int rsel = lane & 15;
    const int rsub = lane >> 4;

    f32x4 accN[4];
    f32x4 accL;
    #pragma unroll
    for (int nb = 0; nb < 4; ++nb) { accN[nb][0]=0.f; accN[nb][1]=0.f; accN[nb][2]=0.f; accN[nb][3]=0.f; }
    accL[0]=0.f; accL[1]=0.f; accL[2]=0.f; accL[3]=0.f;

    s16x8 ones;
    #pragma unroll
    for (int e = 0; e < 8; ++e) ones[e] = (short)0x3F80;  // bf16 1.0

    // ---- build 16x64 W tile: int4 adj loads (16B/lane), 4 rows/iteration
    const float4 sj4 = ((const float4*)s_buf)[(jb >> 2) + rsel];
    const int4* adj4 = (const int4*)adj;
    #pragma unroll
    for (int r4 = 0; r4 < 4; ++r4) {
        const int row = r4 * 4 + rsub;
        const int i = i0 + row;
        const float si = s_buf[i];
        int4 a = adj4[(size_t)i * (N_ROWS / 4) + (jb >> 2) + rsel];
        ushort4 pk;
        { float z = si + sj4.x + mub; float e = z > 0.f ? z : ALPHA * z; pk.x = a.x ? f2bf(__expf(e)) : 0; }
        { float z = si + sj4.y + mub; float e = z > 0.f ? z : ALPHA * z; pk.y = a.y ? f2bf(__expf(e)) : 0; }
        { float z = si + sj4.z + mub; float e = z > 0.f ? z : ALPHA * z; pk.z = a.z ? f2bf(__expf(e)) : 0; }
        { float z = si + sj4.w + mub; float e = z > 0.f ? z : ALPHA * z; pk.w = a.w ? f2bf(__expf(e)) : 0; }
        *(ushort4*)&Wt[w][row][rsel * 4] = pk;
    }

    // ---- A fragments (same-wave LDS dependency; compiler emits lgkmcnt)
    s16x8 a0 = *(const s16x8*)&Wt[w][rsel][rsub * 8];
    s16x8 a1 = *(const s16x8*)&Wt[w][rsel][32 + rsub * 8];

    accL = __builtin_amdgcn_mfma_f32_16x16x32_bf16(a0, ones, accL, 0, 0, 0);
    accL = __builtin_amdgcn_mfma_f32_16x16x32_bf16(a1, ones, accL, 0, 0, 0);
    #pragma unroll
    for (int nb = 0; nb < 4; ++nb) {
        const unsigned short* hr = HhiT + (size_t)(nb * 16 + rsel) * N_ROWS + jb + rsub * 8;
        s16x8 b0 = *(const s16x8*)hr;
        s16x8 b1 = *(const s16x8*)(hr + 32);
        accN[nb] = __builtin_amdgcn_mfma_f32_16x16x32_bf16(a0, b0, accN[nb], 0, 0, 0);
        accN[nb] = __builtin_amdgcn_mfma_f32_16x16x32_bf16(a1, b1, accN[nb], 0, 0, 0);
        const unsigned short* lr = HloT + (size_t)(nb * 16 + rsel) * N_ROWS + jb + rsub * 8;
        s16x8 c0 = *(const s16x8*)lr;
        s16x8 c1 = *(const s16x8*)(lr + 32);
        accN[nb] = __builtin_amdgcn_mfma_f32_16x16x32_bf16(a0, c0, accN[nb], 0, 0, 0);
        accN[nb] = __builtin_amdgcn_mfma_f32_16x16x32_bf16(a1, c1, accN[nb], 0, 0, 0);
    }

    // ---- cross-wave combine
    #pragma unroll
    for (int nb = 0; nb < 4; ++nb) cN[w][nb][lane] = accN[nb];
    cL[w][lane] = accL;
    __syncthreads();

    {   // wave w handles column-block nb = w; sc1 agent stores
        f32x4 n = cN[0][w][lane] + cN[1][w][lane] + cN[2][w][lane] + cN[3][w][lane];
        float* np = numP + (size_t)slab * (N_ROWS * D_OUT);
        #pragma unroll
        for (int r = 0; r < 4; ++r)
            st_agent_f32(&np[(i0 + rsub * 4 + r) * D_OUT + w * 16 + rsel], n[r]);
    }
    if (w == 0) {
        f32x4 l = cL[0][lane] + cL[1][lane] + cL[2][lane] + cL[3][lane];
        if (rsel == 0) {
            // l_p layout: [stripe][slab][16] -> stripe-exclusive 512B
            #pragma unroll
            for (int r = 0; r < 4; ++r)
                st_agent_f32(&l_p[stripe * 128 + slab * 16 + rsub * 4 + r], l[r]);
        }
    }

    // ---- stripe completion: last of 8 blocks finishes
    __syncthreads();                       // drain this block's sc1 stores
    if (tid == 0) {
        int old = atomicAdd(&bar[stripe], 1);
        finisher = (old == 7);
    }
    __syncthreads();

    if (finisher) {
        // 1024 outputs (16 rows x 64 d), 256 threads -> f32x4 per thread
        const int idx = tid * 4;
        const int r = idx >> 6;
        const int c = idx & 63;
        const int row = i0 + r;
        f32x4 n = {0.f, 0.f, 0.f, 0.f};
        float l = 0.f;
        #pragma unroll
        for (int sl = 0; sl < JSLAB; ++sl) {
            const f32x4* np = (const f32x4*)(numP + (size_t)sl * (N_ROWS * D_OUT)
                                             + row * D_OUT + c);
            n += *np;
            l += l_p[stripe * 128 + sl * 16 + r];
        }
        const float inv = 1.f / l;
        f32x4 o;
        #pragma unroll
        for (int e = 0; e < 4; ++e) {
            float v = n[e] * inv;
            o[e] = v > 0.f ? v : expm1f(v);
        }
        *(f32x4*)&out[row * D_OUT + c] = o;
    }
}

// ---------------------------------------------------------------------------
extern "C" void kernel_launch(void* const* d_in, const int* in_sizes, int n_in,
                              void* d_out, int out_size, void* d_ws, size_t ws_size,
                              hipStream_t stream)
{
    const float* F    = (const float*)d_in[0];
    const int*   adj  = (const int*)d_in[1];
    const float* phiW = (const float*)d_in[2];
    const float* phiB = (const float*)d_in[3];
    const float* lnG  = (const float*)d_in[4];
    const float* lnB  = (const float*)d_in[5];
    const float* muW  = (const float*)d_in[6];
    const float* muB  = (const float*)d_in[7];
    float* out = (float*)d_out;

    int*   bar  = (int*)d_ws;                           // 128 stripe counters
    float* ws   = (float*)d_ws + 2048;
    float* s    = ws;                                   // 2048 f32
    float* l_p  = ws + N_ROWS;                          // 128*128 f32 (padded)
    float* numP = l_p + 128 * 128;                      // JSLAB*2048*64 f32
    unsigned short* HhiT = (unsigned short*)(numP + (size_t)JSLAB * N_ROWS * D_OUT);
    unsigned short* HloT = HhiT + (size_t)D_OUT * N_ROWS;

    hipMemsetAsync(bar, 0, 2048 * sizeof(int), stream); // reset counters

    k1_h_s<<<dim3(512), dim3(256), 0, stream>>>(F, phiW, phiB, lnG, lnB, muW,
                                                s, HhiT, HloT);
    k2_attn<<<dim3(128 * JSLAB), dim3(256), 0, stream>>>(adj, s, HhiT, HloT, muB,
                                                         bar, numP, l_p, out);
}

// Round 7
// 28.767 us; speedup vs baseline: 3.7116x; 1.1260x over previous
//
#include <hip/hip_runtime.h>
#include <hip/hip_bf16.h>

#define N_ROWS 2048
#define D_IN   256
#define D_OUT  64
#define JSLAB  8
#define ALPHA  0.2f
#define LN_EPS 1e-5f

typedef __attribute__((ext_vector_type(4))) float f32x4;
typedef __attribute__((ext_vector_type(8))) short s16x8;

static __device__ __forceinline__ unsigned short f2bf(float x) {
    unsigned u = __float_as_uint(x);
    unsigned r = (u + 0x7FFFu + ((u >> 16) & 1u)) >> 16;   // RTN-even
    return (unsigned short)r;
}
static __device__ __forceinline__ float bf2f(unsigned short u) {
    return __uint_as_float(((unsigned)u) << 16);
}

// ---------------------------------------------------------------------------
// K1: h = LN(F @ phiW^T + phiB); s = h . muW; H^T bf16 hi/lo planes.
// 256 blocks x 256 threads, 8 rows/block (2 rows/wave). Single 64KB phiW
// stage, column-rotation swizzle (conflict-free b128). F loads are
// wave-uniform (s_load). Plain stores; K1->K2 visibility via dispatch
// boundary (verified passing in R2/R6).
// ---------------------------------------------------------------------------
__global__ __launch_bounds__(256) void k1_h_s(
    const float* __restrict__ F, const float* __restrict__ phiW,
    const float* __restrict__ phiB, const float* __restrict__ lnG,
    const float* __restrict__ lnB, const float* __restrict__ muW,
    float* __restrict__ s_buf, unsigned short* __restrict__ HhiT,
    unsigned short* __restrict__ HloT)
{
    __shared__ f32x4 phiS[64 * 64];          // 64 KB, column-rotated
    __shared__ unsigned short Thi[64][8];
    __shared__ unsigned short Tlo[64][8];

    const int tid  = threadIdx.x;
    const int w    = tid >> 6;
    const int lane = tid & 63;
    const int i_base = blockIdx.x * 8;
    const int r0 = i_base + w * 2;             // 2 rows per wave

    const f32x4* phiW4 = (const f32x4*)phiW;   // [64][64] f32x4
    const f32x4* F4    = (const f32x4*)F;      // [2048][64] f32x4

    #pragma unroll
    for (int t = 0; t < 16; ++t) {             // stage 64KB, rotated cols
        int idx = tid + t * 256;
        int d = idx >> 6, g = idx & 63;
        phiS[(d << 6) | ((g + d) & 63)] = phiW4[idx];
    }
    __syncthreads();

    float acc[2] = {0.f, 0.f};
    #pragma unroll 8
    for (int g = 0; g < 64; ++g) {
        f32x4 p = phiS[(lane << 6) | ((g + lane) & 63)];
        #pragma unroll
        for (int rr = 0; rr < 2; ++rr) {
            f32x4 f = F4[(r0 + rr) * 64 + g];  // wave-uniform address
            acc[rr] += p.x * f.x + p.y * f.y + p.z * f.z + p.w * f.w;
        }
    }

    const float pb = phiB[lane], gg = lnG[lane], bb = lnB[lane], mw = muW[lane];

    #pragma unroll
    for (int rr = 0; rr < 2; ++rr) {
        float h = acc[rr] + pb;
        float m = h;
        #pragma unroll
        for (int off = 32; off >= 1; off >>= 1) m += __shfl_xor(m, off);
        m *= (1.f / 64.f);
        float c = h - m;
        float v = c * c;
        #pragma unroll
        for (int off = 32; off >= 1; off >>= 1) v += __shfl_xor(v, off);
        v *= (1.f / 64.f);
        float hn = c * rsqrtf(v + LN_EPS) * gg + bb;
        float sp = hn * mw;
        #pragma unroll
        for (int off = 32; off >= 1; off >>= 1) sp += __shfl_xor(sp, off);
        if (lane == 0) s_buf[r0 + rr] = sp;
        unsigned short hi = f2bf(hn);
        unsigned short lo = f2bf(hn - bf2f(hi));
        Thi[lane][w * 2 + rr] = hi;
        Tlo[lane][w * 2 + rr] = lo;
    }
    __syncthreads();
    if (tid < 128) {   // transposed store: H^T[d][i_base .. i_base+7]
        int d = tid >> 1, half = tid & 1;
        ushort4 vh = *(const ushort4*)&Thi[d][half * 4];
        *(ushort4*)&HhiT[d * N_ROWS + i_base + half * 4] = vh;
        ushort4 vl = *(const ushort4*)&Tlo[d][half * 4];
        *(ushort4*)&HloT[d * N_ROWS + i_base + half * 4] = vl;
    }
}

// ---------------------------------------------------------------------------
// K2: 1024 blocks x 256 threads; block = one (stripe, slab) task:
// 16 rows x 256 j; wave w owns a 16x64 W tile -> MFMA numerator + ones-
// denominator, cross-wave LDS combine, plain partial stores.
// LDS ~30KB -> 4 blocks/CU (16 waves/CU).
// ---------------------------------------------------------------------------
__global__ __launch_bounds__(256) void k2_attn(
    const int* __restrict__ adj, const float* __restrict__ s_buf,
    const unsigned short* __restrict__ HhiT, const unsigned short* __restrict__ HloT,
    const float* __restrict__ muB,
    float* __restrict__ numP, float* __restrict__ l_p)
{
    __shared__ __align__(16) unsigned short Wt[4][16][72];
    __shared__ f32x4 cN[4][4][64];
    __shared__ f32x4 cL[4][64];

    const int tid  = threadIdx.x;
    const int w    = tid >> 6;
    const int lane = tid & 63;
    const int stripe = blockIdx.x >> 3;        // 0..127
    const int slab   = blockIdx.x & 7;         // 0..7
    const int i0 = stripe * 16;
    const int jb = slab * 256 + w * 64;
    const float mub = muB[0];

    const int rsel = lane & 15;
    const int rsub = lane >> 4;

    f32x4 accN[4];
    f32x4 accL;
    #pragma unroll
    for (int nb = 0; nb < 4; ++nb) { accN[nb][0]=0.f; accN[nb][1]=0.f; accN[nb][2]=0.f; accN[nb][3]=0.f; }
    accL[0]=0.f; accL[1]=0.f; accL[2]=0.f; accL[3]=0.f;

    s16x8 ones;
    #pragma unroll
    for (int e = 0; e < 8; ++e) ones[e] = (short)0x3F80;  // bf16 1.0

    // ---- build 16x64 W tile: int4 adj loads (16B/lane), 4 rows/iteration
    const float4 sj4 = ((const float4*)s_buf)[(jb >> 2) + rsel];
    const int4* adj4 = (const int4*)adj;
    #pragma unroll
    for (int r4 = 0; r4 < 4; ++r4) {
        const int row = r4 * 4 + rsub;
        const int i = i0 + row;
        const float si = s_buf[i];
        int4 a = adj4[(size_t)i * (N_ROWS / 4) + (jb >> 2) + rsel];
        ushort4 pk;
        { float z = si + sj4.x + mub; float e = z > 0.f ? z : ALPHA * z; pk.x = a.x ? f2bf(__expf(e)) : 0; }
        { float z = si + sj4.y + mub; float e = z > 0.f ? z : ALPHA * z; pk.y = a.y ? f2bf(__expf(e)) : 0; }
        { float z = si + sj4.z + mub; float e = z > 0.f ? z : ALPHA * z; pk.z = a.z ? f2bf(__expf(e)) : 0; }
        { float z = si + sj4.w + mub; float e = z > 0.f ? z : ALPHA * z; pk.w = a.w ? f2bf(__expf(e)) : 0; }
        *(ushort4*)&Wt[w][row][rsel * 4] = pk;
    }

    // ---- A fragments (same-wave LDS dependency; compiler emits lgkmcnt)
    s16x8 a0 = *(const s16x8*)&Wt[w][rsel][rsub * 8];
    s16x8 a1 = *(const s16x8*)&Wt[w][rsel][32 + rsub * 8];

    accL = __builtin_amdgcn_mfma_f32_16x16x32_bf16(a0, ones, accL, 0, 0, 0);
    accL = __builtin_amdgcn_mfma_f32_16x16x32_bf16(a1, ones, accL, 0, 0, 0);
    #pragma unroll
    for (int nb = 0; nb < 4; ++nb) {
        const unsigned short* hr = HhiT + (size_t)(nb * 16 + rsel) * N_ROWS + jb + rsub * 8;
        s16x8 b0 = *(const s16x8*)hr;
        s16x8 b1 = *(const s16x8*)(hr + 32);
        accN[nb] = __builtin_amdgcn_mfma_f32_16x16x32_bf16(a0, b0, accN[nb], 0, 0, 0);
        accN[nb] = __builtin_amdgcn_mfma_f32_16x16x32_bf16(a1, b1, accN[nb], 0, 0, 0);
        const unsigned short* lr = HloT + (size_t)(nb * 16 + rsel) * N_ROWS + jb + rsub * 8;
        s16x8 c0 = *(const s16x8*)lr;
        s16x8 c1 = *(const s16x8*)(lr + 32);
        accN[nb] = __builtin_amdgcn_mfma_f32_16x16x32_bf16(a0, c0, accN[nb], 0, 0, 0);
        accN[nb] = __builtin_amdgcn_mfma_f32_16x16x32_bf16(a1, c1, accN[nb], 0, 0, 0);
    }

    // ---- cross-wave combine
    #pragma unroll
    for (int nb = 0; nb < 4; ++nb) cN[w][nb][lane] = accN[nb];
    cL[w][lane] = accL;
    __syncthreads();

    {   // wave w handles column-block nb = w
        f32x4 n = cN[0][w][lane] + cN[1][w][lane] + cN[2][w][lane] + cN[3][w][lane];
        float* np = numP + (size_t)slab * (N_ROWS * D_OUT);
        #pragma unroll
        for (int r = 0; r < 4; ++r)
            np[(i0 + rsub * 4 + r) * D_OUT + w * 16 + rsel] = n[r];
    }
    if (w == 0) {
        f32x4 l = cL[0][lane] + cL[1][lane] + cL[2][lane] + cL[3][lane];
        if (rsel == 0) {
            // l_p layout: [stripe][slab][16]
            #pragma unroll
            for (int r = 0; r < 4; ++r)
                l_p[stripe * 128 + slab * 16 + rsub * 4 + r] = l[r];
        }
    }
}

// ---------------------------------------------------------------------------
// K3: combine j-slab partials, normalize, ELU. 128 blocks x 256 threads,
// f32x4 per thread.
// ---------------------------------------------------------------------------
__global__ __launch_bounds__(256) void k3_combine(
    const float* __restrict__ numP, const float* __restrict__ l_p,
    float* __restrict__ out)
{
    const int idx = (blockIdx.x * 256 + threadIdx.x) * 4;
    const int row = idx >> 6;
    const int stripe = row >> 4;
    const int r = row & 15;
    f32x4 n = {0.f, 0.f, 0.f, 0.f};
    float l = 0.f;
    #pragma unroll
    for (int sl = 0; sl < JSLAB; ++sl) {
        n += *(const f32x4*)(numP + (size_t)sl * (N_ROWS * D_OUT) + idx);
        l += l_p[stripe * 128 + sl * 16 + r];
    }
    const float inv = 1.f / l;
    f32x4 o;
    #pragma unroll
    for (int e = 0; e < 4; ++e) {
        float v = n[e] * inv;
        o[e] = v > 0.f ? v : expm1f(v);
    }
    *(f32x4*)&out[idx] = o;
}

// ---------------------------------------------------------------------------
extern "C" void kernel_launch(void* const* d_in, const int* in_sizes, int n_in,
                              void* d_out, int out_size, void* d_ws, size_t ws_size,
                              hipStream_t stream)
{
    const float* F    = (const float*)d_in[0];
    const int*   adj  = (const int*)d_in[1];
    const float* phiW = (const float*)d_in[2];
    const float* phiB = (const float*)d_in[3];
    const float* lnG  = (const float*)d_in[4];
    const float* lnB  = (const float*)d_in[5];
    const float* muW  = (const float*)d_in[6];
    const float* muB  = (const float*)d_in[7];
    float* out = (float*)d_out;

    float* ws   = (float*)d_ws;
    float* s    = ws;                                   // 2048 f32
    float* l_p  = ws + N_ROWS;                          // 128*128 f32
    float* numP = l_p + 128 * 128;                      // JSLAB*2048*64 f32
    unsigned short* HhiT = (unsigned short*)(numP + (size_t)JSLAB * N_ROWS * D_OUT);
    unsigned short* HloT = HhiT + (size_t)D_OUT * N_ROWS;

    k1_h_s<<<dim3(256), dim3(256), 0, stream>>>(F, phiW, phiB, lnG, lnB, muW,
                                                s, HhiT, HloT);
    k2_attn<<<dim3(128 * JSLAB), dim3(256), 0, stream>>>(adj, s, HhiT, HloT, muB,
                                                         numP, l_p);
    k3_combine<<<dim3(128), dim3(256), 0, stream>>>(numP, l_p, out);
}